// Round 4
// baseline (814.852 us; speedup 1.0000x reference)
//
#include <hip/hip_runtime.h>

#define N_NODES 50000
#define N_EDGES 640000
#define HD 128
#define TILE_N 128
#define NSCB 196  // ceil(50000/256)

// ---------------------------------------------------------------------------
// Register-tiled fp32 GEMM building blocks.
// Block = 256 threads = (jg = tid&15) x (ng = tid>>4).
// Thread tile: 8 nodes (ng*8+i) x 8 cols {4jg..4jg+3, 64+4jg..64+4jg+3}.
// S tile [128 nodes][128 d] in LDS, float4 slot XOR-swizzled by (node>>3)&3
// so the 4 node-groups of a wave read 4 distinct float4s (16 banks, free).
// W is NOT staged in LDS: a wave's W fetch is 16 unique float4 = 256 B
// contiguous (4-way broadcast), L1/L2-resident (64 KB), on the VMEM pipe.
// => LDS/block = 64 KB -> 2 blocks/CU = 2 waves/SIMD for latency hiding.
// ---------------------------------------------------------------------------

__device__ __forceinline__ void fma4(float4& a, float s, const float4& w) {
  a.x = fmaf(s, w.x, a.x);
  a.y = fmaf(s, w.y, a.y);
  a.z = fmaf(s, w.z, a.z);
  a.w = fmaf(s, w.w, a.w);
}

// W from global (L1/L2), register double-buffered; S from swizzled LDS.
__device__ __forceinline__ void mm_tile_g(const float* Ssh, const float* __restrict__ Wg,
                                          int jg, int ng, float4 acc0[8], float4 acc1[8]) {
  const float4* S4 = (const float4*)Ssh;
  const float4* W4 = (const float4*)Wg;
  const int ngs = ng & 3;
  float4 w0[4], w1[4];
#pragma unroll
  for (int k = 0; k < 4; ++k) {
    w0[k] = W4[k * 32 + jg];
    w1[k] = W4[k * 32 + 16 + jg];
  }
#pragma unroll 4
  for (int t = 0; t < 32; ++t) {
    float4 nw0[4], nw1[4];
    if (t < 31) {
#pragma unroll
      for (int k = 0; k < 4; ++k) {
        nw0[k] = W4[(4 * (t + 1) + k) * 32 + jg];
        nw1[k] = W4[(4 * (t + 1) + k) * 32 + 16 + jg];
      }
    }
#pragma unroll
    for (int i = 0; i < 8; ++i) {
      float4 sv = S4[(ng * 8 + i) * 32 + (t ^ ngs)];
      fma4(acc0[i], sv.x, w0[0]);
      fma4(acc1[i], sv.x, w1[0]);
      fma4(acc0[i], sv.y, w0[1]);
      fma4(acc1[i], sv.y, w1[1]);
      fma4(acc0[i], sv.z, w0[2]);
      fma4(acc1[i], sv.z, w1[2]);
      fma4(acc0[i], sv.w, w0[3]);
      fma4(acc1[i], sv.w, w1[3]);
    }
#pragma unroll
    for (int k = 0; k < 4; ++k) {
      w0[k] = nw0[k];
      w1[k] = nw1[k];
    }
  }
}

// Stage 128 rows of src[N][128] into swizzled S tile; zero-fill past N.
// 128 nodes x 32 float4 = 4096 float4 = 16 per thread.
__device__ __forceinline__ void stage_S(const float* __restrict__ src, float* Ssh,
                                        int bnode0, int tid) {
  const float4* g = (const float4*)src;
  float4* l = (float4*)Ssh;
#pragma unroll
  for (int c = 0; c < 16; ++c) {
    int f4 = c * 256 + tid;
    int nl = f4 >> 5;
    int t = f4 & 31;
    int gn = bnode0 + nl;
    float4 v = make_float4(0.f, 0.f, 0.f, 0.f);
    if (gn < N_NODES) v = g[(size_t)gn * 32 + t];
    int sw = (nl >> 3) & 3;
    l[(f4 & ~31) | (t ^ sw)] = v;
  }
}

// Write thread tile into swizzled S (for chained GEMMs).
__device__ __forceinline__ void store_tile_S(float* Ssh, int jg, int ng,
                                             const float4 a0[8], const float4 a1[8]) {
  float4* l = (float4*)Ssh;
  const int ngs = ng & 3;
#pragma unroll
  for (int i = 0; i < 8; ++i) {
    int n = ng * 8 + i;
    l[n * 32 + (jg ^ ngs)] = a0[i];
    l[n * 32 + ((16 + jg) ^ ngs)] = a1[i];
  }
}

__device__ __forceinline__ void store_tile_G(float* __restrict__ dst, int bnode0, int jg,
                                             int ng, const float4 a0[8], const float4 a1[8]) {
  float4* g = (float4*)dst;
#pragma unroll
  for (int i = 0; i < 8; ++i) {
    int gn = bnode0 + ng * 8 + i;
    if (gn < N_NODES) {
      g[(size_t)gn * 32 + jg] = a0[i];
      g[(size_t)gn * 32 + 16 + jg] = a1[i];
    }
  }
}

// h0 = x@Wp + bp ; a = h0@Wm[:H] ; b = h0@Wm[H:] + bm
__global__ __launch_bounds__(256, 2) void k_proj(
    const float* __restrict__ x, const float* __restrict__ Wp,
    const float* __restrict__ bp, const float* __restrict__ Wm,
    const float* __restrict__ bm, float* __restrict__ h0,
    float* __restrict__ a, float* __restrict__ b) {
  __shared__ float Ssh[TILE_N * HD];
  const int tid = threadIdx.x;
  const int jg = tid & 15, ng = tid >> 4;
  const int bnode0 = blockIdx.x * TILE_N;

  stage_S(x, Ssh, bnode0, tid);
  __syncthreads();

  float4 a0[8], a1[8];
  {
    float4 v0 = ((const float4*)bp)[jg], v1 = ((const float4*)bp)[16 + jg];
#pragma unroll
    for (int i = 0; i < 8; ++i) { a0[i] = v0; a1[i] = v1; }
  }
  mm_tile_g(Ssh, Wp, jg, ng, a0, a1);  // h0
  __syncthreads();                     // all x-tile reads done
  store_tile_S(Ssh, jg, ng, a0, a1);
  store_tile_G(h0, bnode0, jg, ng, a0, a1);
  __syncthreads();                     // h0 tile visible

#pragma unroll
  for (int i = 0; i < 8; ++i) {
    a0[i] = make_float4(0.f, 0.f, 0.f, 0.f);
    a1[i] = make_float4(0.f, 0.f, 0.f, 0.f);
  }
  mm_tile_g(Ssh, Wm, jg, ng, a0, a1);  // a = h0@Wm[:H]
  store_tile_G(a, bnode0, jg, ng, a0, a1);

  {
    float4 v0 = ((const float4*)bm)[jg], v1 = ((const float4*)bm)[16 + jg];
#pragma unroll
    for (int i = 0; i < 8; ++i) { a0[i] = v0; a1[i] = v1; }
  }
  mm_tile_g(Ssh, Wm + HD * HD, jg, ng, a0, a1);  // b = h0@Wm[H:] + bm
  store_tile_G(b, bnode0, jg, ng, a0, a1);
}

__global__ void k_hist(const int* __restrict__ dst, int* __restrict__ deg) {
  int e = blockIdx.x * 256 + threadIdx.x;
  if (e < N_EDGES) atomicAdd(&deg[dst[e]], 1);
}

__global__ __launch_bounds__(256) void k_scan1(const int* __restrict__ deg,
                                               int* __restrict__ bsum) {
  __shared__ int sh[256];
  int i = blockIdx.x * 256 + threadIdx.x;
  sh[threadIdx.x] = (i < N_NODES) ? deg[i] : 0;
  __syncthreads();
  for (int off = 128; off > 0; off >>= 1) {
    if (threadIdx.x < off) sh[threadIdx.x] += sh[threadIdx.x + off];
    __syncthreads();
  }
  if (threadIdx.x == 0) bsum[blockIdx.x] = sh[0];
}

__global__ __launch_bounds__(256) void k_scan2(const int* __restrict__ bsum,
                                               int* __restrict__ boff,
                                               int* __restrict__ row_start) {
  __shared__ int sh[256];
  int t = threadIdx.x;
  int v = (t < NSCB) ? bsum[t] : 0;
  sh[t] = v;
  __syncthreads();
  for (int off = 1; off < 256; off <<= 1) {
    int add = (t >= off) ? sh[t - off] : 0;
    __syncthreads();
    sh[t] += add;
    __syncthreads();
  }
  if (t < NSCB) boff[t] = sh[t] - v;  // exclusive
  if (t == 255) row_start[N_NODES] = sh[255];
}

__global__ __launch_bounds__(256) void k_scan3(const int* __restrict__ deg,
                                               const int* __restrict__ boff,
                                               int* __restrict__ row_start,
                                               int* __restrict__ cursor) {
  __shared__ int sh[256];
  int t = threadIdx.x;
  int i = blockIdx.x * 256 + t;
  int v = (i < N_NODES) ? deg[i] : 0;
  sh[t] = v;
  __syncthreads();
  for (int off = 1; off < 256; off <<= 1) {
    int add = (t >= off) ? sh[t - off] : 0;
    __syncthreads();
    sh[t] += add;
    __syncthreads();
  }
  if (i < N_NODES) {
    int ex = boff[blockIdx.x] + sh[t] - v;
    row_start[i] = ex;
    cursor[i] = ex;
  }
}

__global__ void k_scatter(const int* __restrict__ src, const int* __restrict__ dst,
                          int* __restrict__ cursor, int* __restrict__ es) {
  int e = blockIdx.x * 256 + threadIdx.x;
  if (e < N_EDGES) {
    int d = dst[e];
    int pos = atomicAdd(&cursor[d], 1);
    es[pos] = src[e];
  }
}

// pooled[n] = mean over incoming edges of relu(a[src] + b[n]) (bm already in b)
__global__ __launch_bounds__(256) void k_agg(const float* __restrict__ a,
                                             const float* __restrict__ b,
                                             const int* __restrict__ es,
                                             const int* __restrict__ row_start,
                                             float* __restrict__ pooled) {
  const int node = blockIdx.x * 4 + (threadIdx.x >> 6);
  const int lane = threadIdx.x & 63;
  const int s = row_start[node];
  const int e = row_start[node + 1];
  const float2 bv = ((const float2*)(b + (size_t)node * HD))[lane];
  float ax = 0.f, ay = 0.f;
  int i = s;
  for (; i + 4 <= e; i += 4) {
    int s0 = es[i], s1 = es[i + 1], s2 = es[i + 2], s3 = es[i + 3];
    float2 a0 = ((const float2*)(a + (size_t)s0 * HD))[lane];
    float2 a1 = ((const float2*)(a + (size_t)s1 * HD))[lane];
    float2 a2 = ((const float2*)(a + (size_t)s2 * HD))[lane];
    float2 a3 = ((const float2*)(a + (size_t)s3 * HD))[lane];
    ax += fmaxf(a0.x + bv.x, 0.f);
    ay += fmaxf(a0.y + bv.y, 0.f);
    ax += fmaxf(a1.x + bv.x, 0.f);
    ay += fmaxf(a1.y + bv.y, 0.f);
    ax += fmaxf(a2.x + bv.x, 0.f);
    ay += fmaxf(a2.y + bv.y, 0.f);
    ax += fmaxf(a3.x + bv.x, 0.f);
    ay += fmaxf(a3.y + bv.y, 0.f);
  }
  for (; i < e; ++i) {
    int s0 = es[i];
    float2 a0 = ((const float2*)(a + (size_t)s0 * HD))[lane];
    ax += fmaxf(a0.x + bv.x, 0.f);
    ay += fmaxf(a0.y + bv.y, 0.f);
  }
  const float inv = 1.f / fmaxf((float)(e - s), 1.f);
  ((float2*)(pooled + (size_t)node * HD))[lane] = make_float2(ax * inv, ay * inv);
}

// upd = h0@Wu[:H] + pooled@Wu[H:] + bu ; hn = relu(h0+upd) ; LN ; graph-sum
__global__ __launch_bounds__(256, 2) void k_upd(
    const float* __restrict__ h0, const float* __restrict__ pooled,
    const float* __restrict__ Wu, const float* __restrict__ bu,
    const float* __restrict__ gamma, const float* __restrict__ beta,
    float* __restrict__ gsum) {
  __shared__ float Ssh[TILE_N * HD];
  const int tid = threadIdx.x;
  const int jg = tid & 15, ng = tid >> 4;
  const int ngs = ng & 3;
  const int bnode0 = blockIdx.x * TILE_N;

  stage_S(pooled, Ssh, bnode0, tid);
  __syncthreads();

  float4 a0[8], a1[8];
  {
    float4 v0 = ((const float4*)bu)[jg], v1 = ((const float4*)bu)[16 + jg];
#pragma unroll
    for (int i = 0; i < 8; ++i) { a0[i] = v0; a1[i] = v1; }
  }
  mm_tile_g(Ssh, Wu + HD * HD, jg, ng, a0, a1);  // pooled@Wu[H:] + bu
  __syncthreads();
  stage_S(h0, Ssh, bnode0, tid);
  __syncthreads();
  mm_tile_g(Ssh, Wu, jg, ng, a0, a1);  // += h0@Wu[:H]

  // residual + relu + LayerNorm + masked graph partial
  float4 gam0 = ((const float4*)gamma)[jg], gam1 = ((const float4*)gamma)[16 + jg];
  float4 bet0 = ((const float4*)beta)[jg], bet1 = ((const float4*)beta)[16 + jg];
  float4 gpa = make_float4(0.f, 0.f, 0.f, 0.f);
  float4 gpb = make_float4(0.f, 0.f, 0.f, 0.f);
  const float4* S4 = (const float4*)Ssh;
#pragma unroll
  for (int i = 0; i < 8; ++i) {
    int n = ng * 8 + i;
    float4 h0v0 = S4[n * 32 + (jg ^ ngs)];
    float4 h0v1 = S4[n * 32 + ((16 + jg) ^ ngs)];
    float4 v0, v1;
    v0.x = fmaxf(h0v0.x + a0[i].x, 0.f);
    v0.y = fmaxf(h0v0.y + a0[i].y, 0.f);
    v0.z = fmaxf(h0v0.z + a0[i].z, 0.f);
    v0.w = fmaxf(h0v0.w + a0[i].w, 0.f);
    v1.x = fmaxf(h0v1.x + a1[i].x, 0.f);
    v1.y = fmaxf(h0v1.y + a1[i].y, 0.f);
    v1.z = fmaxf(h0v1.z + a1[i].z, 0.f);
    v1.w = fmaxf(h0v1.w + a1[i].w, 0.f);
    float sum = v0.x + v0.y + v0.z + v0.w + v1.x + v1.y + v1.z + v1.w;
    float sq = v0.x * v0.x + v0.y * v0.y + v0.z * v0.z + v0.w * v0.w +
               v1.x * v1.x + v1.y * v1.y + v1.z * v1.z + v1.w * v1.w;
#pragma unroll
    for (int m = 1; m < 16; m <<= 1) {
      sum += __shfl_xor(sum, m);
      sq += __shfl_xor(sq, m);
    }
    float mu = sum * (1.f / 128.f);
    float var = sq * (1.f / 128.f) - mu * mu;
    float rs = rsqrtf(var + 1e-6f);
    if (bnode0 + n < N_NODES) {
      gpa.x += (v0.x - mu) * rs * gam0.x + bet0.x;
      gpa.y += (v0.y - mu) * rs * gam0.y + bet0.y;
      gpa.z += (v0.z - mu) * rs * gam0.z + bet0.z;
      gpa.w += (v0.w - mu) * rs * gam0.w + bet0.w;
      gpb.x += (v1.x - mu) * rs * gam1.x + bet1.x;
      gpb.y += (v1.y - mu) * rs * gam1.y + bet1.y;
      gpb.z += (v1.z - mu) * rs * gam1.z + bet1.z;
      gpb.w += (v1.w - mu) * rs * gam1.w + bet1.w;
    }
  }
  // reduce across the 4 node-groups of the wave (lane bits 4,5)
#pragma unroll
  for (int m = 16; m < 64; m <<= 1) {
    gpa.x += __shfl_xor(gpa.x, m);
    gpa.y += __shfl_xor(gpa.y, m);
    gpa.z += __shfl_xor(gpa.z, m);
    gpa.w += __shfl_xor(gpa.w, m);
    gpb.x += __shfl_xor(gpb.x, m);
    gpb.y += __shfl_xor(gpb.y, m);
    gpb.z += __shfl_xor(gpb.z, m);
    gpb.w += __shfl_xor(gpb.w, m);
  }
  __syncthreads();  // Ssh reads done; reuse as scratch
  float* gs = Ssh;  // [4 waves][128]
  int w = tid >> 6;
  if ((tid & 63) < 16) {
    ((float4*)gs)[w * 32 + jg] = gpa;
    ((float4*)gs)[w * 32 + 16 + jg] = gpb;
  }
  __syncthreads();
  if (tid < HD) {
    float s = gs[tid] + gs[128 + tid] + gs[256 + tid] + gs[384 + tid];
    atomicAdd(&gsum[tid], s);
  }
}

__global__ void k_final(const float* __restrict__ gsum, const float* __restrict__ Wd,
                        const float* __restrict__ bd, float* __restrict__ out) {
  int o = threadIdx.x;
  if (o < 32) {
    float acc = bd[o];
    const float invN = 1.f / (float)N_NODES;
    for (int d = 0; d < HD; ++d) acc = fmaf(gsum[d] * invN, Wd[d * 32 + o], acc);
    out[o] = acc;
  }
}

extern "C" void kernel_launch(void* const* d_in, const int* in_sizes, int n_in,
                              void* d_out, int out_size, void* d_ws, size_t ws_size,
                              hipStream_t stream) {
  (void)in_sizes; (void)n_in; (void)out_size; (void)ws_size;
  const float* x    = (const float*)d_in[0];
  const int* esrc   = (const int*)d_in[1];
  const int* edst   = (const int*)d_in[2];
  const float* Wp   = (const float*)d_in[3];
  const float* bp   = (const float*)d_in[4];
  const float* Wm   = (const float*)d_in[5];
  const float* bm   = (const float*)d_in[6];
  const float* Wu   = (const float*)d_in[7];
  const float* bu   = (const float*)d_in[8];
  const float* gam  = (const float*)d_in[9];
  const float* bet  = (const float*)d_in[10];
  const float* Wd   = (const float*)d_in[11];
  const float* bd   = (const float*)d_in[12];
  float* out = (float*)d_out;

  char* ws = (char*)d_ws;
  size_t off = 0;
  float* h0     = (float*)(ws + off); off += (size_t)N_NODES * HD * 4;
  float* a      = (float*)(ws + off); off += (size_t)N_NODES * HD * 4;
  float* b      = (float*)(ws + off); off += (size_t)N_NODES * HD * 4;
  float* pooled = (float*)(ws + off); off += (size_t)N_NODES * HD * 4;
  int* es       = (int*)(ws + off);   off += (size_t)N_EDGES * 4;
  int* deg      = (int*)(ws + off);   off += (size_t)N_NODES * 4;   // zeroed
  float* gsum   = (float*)(ws + off); off += 128 * 4;               // zeroed (adjacent)
  int* row_start= (int*)(ws + off);   off += (size_t)(N_NODES + 1) * 4;
  int* cursor   = (int*)(ws + off);   off += (size_t)N_NODES * 4;
  int* bsum     = (int*)(ws + off);   off += (size_t)NSCB * 4;
  int* boff     = (int*)(ws + off);   off += (size_t)NSCB * 4;

  hipMemsetAsync(deg, 0, (size_t)(N_NODES + 128) * 4, stream);
  k_proj<<<(N_NODES + TILE_N - 1) / TILE_N, 256, 0, stream>>>(x, Wp, bp, Wm, bm, h0, a, b);
  k_hist<<<(N_EDGES + 255) / 256, 256, 0, stream>>>(edst, deg);
  k_scan1<<<NSCB, 256, 0, stream>>>(deg, bsum);
  k_scan2<<<1, 256, 0, stream>>>(bsum, boff, row_start);
  k_scan3<<<NSCB, 256, 0, stream>>>(deg, boff, row_start, cursor);
  k_scatter<<<(N_EDGES + 255) / 256, 256, 0, stream>>>(esrc, edst, cursor, es);
  k_agg<<<(N_NODES + 3) / 4, 256, 0, stream>>>(a, b, es, row_start, pooled);
  k_upd<<<(N_NODES + TILE_N - 1) / TILE_N, 256, 0, stream>>>(h0, pooled, Wu, bu, gam, bet, gsum);
  k_final<<<1, 64, 0, stream>>>(gsum, Wd, bd, out);
}

// Round 5
// 344.904 us; speedup vs baseline: 2.3625x; 2.3625x over previous
//
#include <hip/hip_runtime.h>

#define N_NODES 50000
#define N_EDGES 640000
#define HD 128
#define TILE_N 128
#define NSCB 196  // ceil(50000/256)

// ---------------------------------------------------------------------------
// Register-tiled fp32 GEMM, K split in halves of 64.
// Block = 256 threads = (jg = tid&15) x (ng = tid>>4).
// Thread tile: 8 nodes (ng*8+i) x 8 cols {4jg..4jg+3, 64+4jg..64+4jg+3}.
// LDS: Sbuf [128 nodes][64 d] (32 KB, float4 slot XOR-swizzled by (node>>3)&3)
//    + Wbuf [64 rows][128 cols] (32 KB, linear) = 64 KB -> 2 blocks/CU.
// W reads: 16 unique consecutive float4, 4-way broadcast, 2-way bank = free.
// S reads: 4 unique float4 (16 distinct banks) x 16-lane broadcast = free.
// Per-phase: 16 t-steps; each t = 4 K-values, 256 FMA/thread.
// VGPR budget kept < 200 (no spill; R4's spill cost 930 MB scratch traffic).
// ---------------------------------------------------------------------------

__device__ __forceinline__ void fma4(float4& a, float s, const float4& w) {
  a.x = fmaf(s, w.x, a.x);
  a.y = fmaf(s, w.y, a.y);
  a.z = fmaf(s, w.z, a.z);
  a.w = fmaf(s, w.w, a.w);
}

// One K-half (64 values = 16 t-steps) of S[128x64] @ W[64x128].
__device__ __forceinline__ void mm_half(const float* Ssh, const float* Wsh,
                                        int jg, int ng, float4 acc0[8], float4 acc1[8]) {
  const float4* S4 = (const float4*)Ssh;
  const float4* W4 = (const float4*)Wsh;
  const int ngs = ng & 3;
#pragma unroll 2
  for (int t = 0; t < 16; ++t) {
    float4 w0[4], w1[4];
#pragma unroll
    for (int k = 0; k < 4; ++k) {
      w0[k] = W4[(4 * t + k) * 32 + jg];
      w1[k] = W4[(4 * t + k) * 32 + 16 + jg];
    }
#pragma unroll
    for (int i = 0; i < 8; ++i) {
      float4 sv = S4[(ng * 8 + i) * 16 + (t ^ ngs)];
      fma4(acc0[i], sv.x, w0[0]);
      fma4(acc1[i], sv.x, w1[0]);
      fma4(acc0[i], sv.y, w0[1]);
      fma4(acc1[i], sv.y, w1[1]);
      fma4(acc0[i], sv.z, w0[2]);
      fma4(acc1[i], sv.z, w1[2]);
      fma4(acc0[i], sv.w, w0[3]);
      fma4(acc1[i], sv.w, w1[3]);
    }
  }
}

// Stage K-half hw (cols hw*64..hw*64+63) of src[N][128] into swizzled Sbuf.
// 128 nodes x 16 float4 = 2048 float4 = 8 per thread.
__device__ __forceinline__ void stage_S_half(const float* __restrict__ src, float* Ssh,
                                             int bnode0, int hw, int tid) {
  const float4* g = (const float4*)src;
  float4* l = (float4*)Ssh;
#pragma unroll
  for (int c = 0; c < 8; ++c) {
    int f4 = c * 256 + tid;
    int nl = f4 >> 4;
    int sl = f4 & 15;
    int gn = bnode0 + nl;
    float4 v = make_float4(0.f, 0.f, 0.f, 0.f);
    if (gn < N_NODES) v = g[(size_t)gn * 32 + hw * 16 + sl];
    int sw = (nl >> 3) & 3;
    l[(f4 & ~15) | (sl ^ sw)] = v;
  }
}

// Stage 64 rows x 128 cols of W (row-major) = 2048 float4, linear.
__device__ __forceinline__ void stage_W_half(const float* __restrict__ srcRow0,
                                             float* Wsh, int tid) {
  const float4* g = (const float4*)srcRow0;
  float4* l = (float4*)Wsh;
#pragma unroll
  for (int c = 0; c < 8; ++c) l[c * 256 + tid] = g[c * 256 + tid];
}

// Write one col-half of the thread tile into swizzled Sbuf (reg -> LDS chain).
__device__ __forceinline__ void store_half_S(float* Ssh, int jg, int ng,
                                             const float4 acc[8]) {
  float4* l = (float4*)Ssh;
  const int ngs = ng & 3;
#pragma unroll
  for (int i = 0; i < 8; ++i) l[(ng * 8 + i) * 16 + (jg ^ ngs)] = acc[i];
}

__device__ __forceinline__ void store_tile_G(float* __restrict__ dst, int bnode0, int jg,
                                             int ng, const float4 a0[8], const float4 a1[8]) {
  float4* g = (float4*)dst;
#pragma unroll
  for (int i = 0; i < 8; ++i) {
    int gn = bnode0 + ng * 8 + i;
    if (gn < N_NODES) {
      g[(size_t)gn * 32 + jg] = a0[i];
      g[(size_t)gn * 32 + 16 + jg] = a1[i];
    }
  }
}

// h0 = x@Wp + bp ; a = h0@Wm[:H] ; b = h0@Wm[H:] + bm
__global__ __launch_bounds__(256, 2) void k_proj(
    const float* __restrict__ x, const float* __restrict__ Wp,
    const float* __restrict__ bp, const float* __restrict__ Wm,
    const float* __restrict__ bm, float* __restrict__ h0,
    float* __restrict__ a, float* __restrict__ b) {
  __shared__ float Ssh[TILE_N * 64];
  __shared__ float Wsh[64 * HD];
  const int tid = threadIdx.x;
  const int jg = tid & 15, ng = tid >> 4;
  const int bnode0 = blockIdx.x * TILE_N;

  float4 a0[8], a1[8];
  {
    float4 v0 = ((const float4*)bp)[jg], v1 = ((const float4*)bp)[16 + jg];
#pragma unroll
    for (int i = 0; i < 8; ++i) { a0[i] = v0; a1[i] = v1; }
  }
  // P1: x half0 @ Wp[0:64]
  stage_S_half(x, Ssh, bnode0, 0, tid);
  stage_W_half(Wp, Wsh, tid);
  __syncthreads();
  mm_half(Ssh, Wsh, jg, ng, a0, a1);
  __syncthreads();
  // P2: x half1 @ Wp[64:]
  stage_S_half(x, Ssh, bnode0, 1, tid);
  stage_W_half(Wp + 64 * HD, Wsh, tid);
  __syncthreads();
  mm_half(Ssh, Wsh, jg, ng, a0, a1);  // a0,a1 = h0 tile
  store_tile_G(h0, bnode0, jg, ng, a0, a1);
  __syncthreads();

  // P3: S = h0 half0 (from regs) @ Wm[0:64] -> partial a
  store_half_S(Ssh, jg, ng, a0);
  stage_W_half(Wm, Wsh, tid);
  __syncthreads();
  float4 c0[8], c1[8];
#pragma unroll
  for (int i = 0; i < 8; ++i) {
    c0[i] = make_float4(0.f, 0.f, 0.f, 0.f);
    c1[i] = make_float4(0.f, 0.f, 0.f, 0.f);
  }
  mm_half(Ssh, Wsh, jg, ng, c0, c1);
  __syncthreads();
  // P4: S = h0 half1 (from regs) @ Wm[64:128] -> a done
  store_half_S(Ssh, jg, ng, a1);
  stage_W_half(Wm + 64 * HD, Wsh, tid);
  __syncthreads();
  mm_half(Ssh, Wsh, jg, ng, c0, c1);
  store_tile_G(a, bnode0, jg, ng, c0, c1);
  __syncthreads();

  // P5: S = h0 half0 (re-staged from global, L2-hot) @ Wm[H:][0:64]
  stage_S_half(h0, Ssh, bnode0, 0, tid);
  stage_W_half(Wm + HD * HD, Wsh, tid);
  __syncthreads();
  {
    float4 v0 = ((const float4*)bm)[jg], v1 = ((const float4*)bm)[16 + jg];
#pragma unroll
    for (int i = 0; i < 8; ++i) { c0[i] = v0; c1[i] = v1; }
  }
  mm_half(Ssh, Wsh, jg, ng, c0, c1);
  __syncthreads();
  // P6: S = h0 half1 @ Wm[H:][64:] -> b done
  stage_S_half(h0, Ssh, bnode0, 1, tid);
  stage_W_half(Wm + HD * HD + 64 * HD, Wsh, tid);
  __syncthreads();
  mm_half(Ssh, Wsh, jg, ng, c0, c1);
  store_tile_G(b, bnode0, jg, ng, c0, c1);
}

__global__ void k_hist(const int* __restrict__ dst, int* __restrict__ deg) {
  int e = blockIdx.x * 256 + threadIdx.x;
  if (e < N_EDGES) atomicAdd(&deg[dst[e]], 1);
}

__global__ __launch_bounds__(256) void k_scan1(const int* __restrict__ deg,
                                               int* __restrict__ bsum) {
  __shared__ int sh[256];
  int i = blockIdx.x * 256 + threadIdx.x;
  sh[threadIdx.x] = (i < N_NODES) ? deg[i] : 0;
  __syncthreads();
  for (int off = 128; off > 0; off >>= 1) {
    if (threadIdx.x < off) sh[threadIdx.x] += sh[threadIdx.x + off];
    __syncthreads();
  }
  if (threadIdx.x == 0) bsum[blockIdx.x] = sh[0];
}

__global__ __launch_bounds__(256) void k_scan2(const int* __restrict__ bsum,
                                               int* __restrict__ boff,
                                               int* __restrict__ row_start) {
  __shared__ int sh[256];
  int t = threadIdx.x;
  int v = (t < NSCB) ? bsum[t] : 0;
  sh[t] = v;
  __syncthreads();
  for (int off = 1; off < 256; off <<= 1) {
    int add = (t >= off) ? sh[t - off] : 0;
    __syncthreads();
    sh[t] += add;
    __syncthreads();
  }
  if (t < NSCB) boff[t] = sh[t] - v;  // exclusive
  if (t == 255) row_start[N_NODES] = sh[255];
}

__global__ __launch_bounds__(256) void k_scan3(const int* __restrict__ deg,
                                               const int* __restrict__ boff,
                                               int* __restrict__ row_start,
                                               int* __restrict__ cursor) {
  __shared__ int sh[256];
  int t = threadIdx.x;
  int i = blockIdx.x * 256 + t;
  int v = (i < N_NODES) ? deg[i] : 0;
  sh[t] = v;
  __syncthreads();
  for (int off = 1; off < 256; off <<= 1) {
    int add = (t >= off) ? sh[t - off] : 0;
    __syncthreads();
    sh[t] += add;
    __syncthreads();
  }
  if (i < N_NODES) {
    int ex = boff[blockIdx.x] + sh[t] - v;
    row_start[i] = ex;
    cursor[i] = ex;
  }
}

__global__ void k_scatter(const int* __restrict__ src, const int* __restrict__ dst,
                          int* __restrict__ cursor, int* __restrict__ es) {
  int e = blockIdx.x * 256 + threadIdx.x;
  if (e < N_EDGES) {
    int d = dst[e];
    int pos = atomicAdd(&cursor[d], 1);
    es[pos] = src[e];
  }
}

// pooled[n] = mean over incoming edges of relu(a[src] + b[n]) (bm already in b)
__global__ __launch_bounds__(256) void k_agg(const float* __restrict__ a,
                                             const float* __restrict__ b,
                                             const int* __restrict__ es,
                                             const int* __restrict__ row_start,
                                             float* __restrict__ pooled) {
  const int node = blockIdx.x * 4 + (threadIdx.x >> 6);
  const int lane = threadIdx.x & 63;
  const int s = row_start[node];
  const int e = row_start[node + 1];
  const float2 bv = ((const float2*)(b + (size_t)node * HD))[lane];
  float ax = 0.f, ay = 0.f;
  int i = s;
  for (; i + 4 <= e; i += 4) {
    int s0 = es[i], s1 = es[i + 1], s2 = es[i + 2], s3 = es[i + 3];
    float2 a0 = ((const float2*)(a + (size_t)s0 * HD))[lane];
    float2 a1 = ((const float2*)(a + (size_t)s1 * HD))[lane];
    float2 a2 = ((const float2*)(a + (size_t)s2 * HD))[lane];
    float2 a3 = ((const float2*)(a + (size_t)s3 * HD))[lane];
    ax += fmaxf(a0.x + bv.x, 0.f);
    ay += fmaxf(a0.y + bv.y, 0.f);
    ax += fmaxf(a1.x + bv.x, 0.f);
    ay += fmaxf(a1.y + bv.y, 0.f);
    ax += fmaxf(a2.x + bv.x, 0.f);
    ay += fmaxf(a2.y + bv.y, 0.f);
    ax += fmaxf(a3.x + bv.x, 0.f);
    ay += fmaxf(a3.y + bv.y, 0.f);
  }
  for (; i < e; ++i) {
    int s0 = es[i];
    float2 a0 = ((const float2*)(a + (size_t)s0 * HD))[lane];
    ax += fmaxf(a0.x + bv.x, 0.f);
    ay += fmaxf(a0.y + bv.y, 0.f);
  }
  const float inv = 1.f / fmaxf((float)(e - s), 1.f);
  ((float2*)(pooled + (size_t)node * HD))[lane] = make_float2(ax * inv, ay * inv);
}

// upd = h0@Wu[:H] + pooled@Wu[H:] + bu ; hn = relu(h0+upd) ; LN ; graph-sum
__global__ __launch_bounds__(256, 2) void k_upd(
    const float* __restrict__ h0, const float* __restrict__ pooled,
    const float* __restrict__ Wu, const float* __restrict__ bu,
    const float* __restrict__ gamma, const float* __restrict__ beta,
    float* __restrict__ gsum) {
  __shared__ float Ssh[TILE_N * 64];
  __shared__ float Wsh[64 * HD];
  const int tid = threadIdx.x;
  const int jg = tid & 15, ng = tid >> 4;
  const int ngs = ng & 3;
  const int bnode0 = blockIdx.x * TILE_N;
  const float4* S4 = (const float4*)Ssh;

  float4 c0[8], c1[8];
  {
    float4 v0 = ((const float4*)bu)[jg], v1 = ((const float4*)bu)[16 + jg];
#pragma unroll
    for (int i = 0; i < 8; ++i) { c0[i] = v0; c1[i] = v1; }
  }
  // P1: pooled half0 @ Wu[H:][0:64]
  stage_S_half(pooled, Ssh, bnode0, 0, tid);
  stage_W_half(Wu + HD * HD, Wsh, tid);
  __syncthreads();
  mm_half(Ssh, Wsh, jg, ng, c0, c1);
  __syncthreads();
  // P2: pooled half1 @ Wu[H:][64:]
  stage_S_half(pooled, Ssh, bnode0, 1, tid);
  stage_W_half(Wu + HD * HD + 64 * HD, Wsh, tid);
  __syncthreads();
  mm_half(Ssh, Wsh, jg, ng, c0, c1);
  __syncthreads();
  // P3: h0 half0 @ Wu[0:64]
  stage_S_half(h0, Ssh, bnode0, 0, tid);
  stage_W_half(Wu, Wsh, tid);
  __syncthreads();
  mm_half(Ssh, Wsh, jg, ng, c0, c1);
  float4 r0[8];
#pragma unroll
  for (int i = 0; i < 8; ++i) r0[i] = S4[(ng * 8 + i) * 16 + (jg ^ ngs)];  // h0 res half0
  __syncthreads();
  // P4: h0 half1 @ Wu[64:]
  stage_S_half(h0, Ssh, bnode0, 1, tid);
  stage_W_half(Wu + 64 * HD, Wsh, tid);
  __syncthreads();
  mm_half(Ssh, Wsh, jg, ng, c0, c1);
  float4 r1[8];
#pragma unroll
  for (int i = 0; i < 8; ++i) r1[i] = S4[(ng * 8 + i) * 16 + (jg ^ ngs)];  // h0 res half1

  // residual + relu + LayerNorm + masked graph partial
  float4 gam0 = ((const float4*)gamma)[jg], gam1 = ((const float4*)gamma)[16 + jg];
  float4 bet0 = ((const float4*)beta)[jg], bet1 = ((const float4*)beta)[16 + jg];
  float4 gpa = make_float4(0.f, 0.f, 0.f, 0.f);
  float4 gpb = make_float4(0.f, 0.f, 0.f, 0.f);
#pragma unroll
  for (int i = 0; i < 8; ++i) {
    int n = ng * 8 + i;
    float4 v0, v1;
    v0.x = fmaxf(r0[i].x + c0[i].x, 0.f);
    v0.y = fmaxf(r0[i].y + c0[i].y, 0.f);
    v0.z = fmaxf(r0[i].z + c0[i].z, 0.f);
    v0.w = fmaxf(r0[i].w + c0[i].w, 0.f);
    v1.x = fmaxf(r1[i].x + c1[i].x, 0.f);
    v1.y = fmaxf(r1[i].y + c1[i].y, 0.f);
    v1.z = fmaxf(r1[i].z + c1[i].z, 0.f);
    v1.w = fmaxf(r1[i].w + c1[i].w, 0.f);
    float sum = v0.x + v0.y + v0.z + v0.w + v1.x + v1.y + v1.z + v1.w;
    float sq = v0.x * v0.x + v0.y * v0.y + v0.z * v0.z + v0.w * v0.w +
               v1.x * v1.x + v1.y * v1.y + v1.z * v1.z + v1.w * v1.w;
#pragma unroll
    for (int m = 1; m < 16; m <<= 1) {
      sum += __shfl_xor(sum, m);
      sq += __shfl_xor(sq, m);
    }
    float mu = sum * (1.f / 128.f);
    float var = sq * (1.f / 128.f) - mu * mu;
    float rs = rsqrtf(var + 1e-6f);
    if (bnode0 + n < N_NODES) {
      gpa.x += (v0.x - mu) * rs * gam0.x + bet0.x;
      gpa.y += (v0.y - mu) * rs * gam0.y + bet0.y;
      gpa.z += (v0.z - mu) * rs * gam0.z + bet0.z;
      gpa.w += (v0.w - mu) * rs * gam0.w + bet0.w;
      gpb.x += (v1.x - mu) * rs * gam1.x + bet1.x;
      gpb.y += (v1.y - mu) * rs * gam1.y + bet1.y;
      gpb.z += (v1.z - mu) * rs * gam1.z + bet1.z;
      gpb.w += (v1.w - mu) * rs * gam1.w + bet1.w;
    }
  }
  // reduce across the 4 node-groups of the wave (lane bits 4,5)
#pragma unroll
  for (int m = 16; m < 64; m <<= 1) {
    gpa.x += __shfl_xor(gpa.x, m);
    gpa.y += __shfl_xor(gpa.y, m);
    gpa.z += __shfl_xor(gpa.z, m);
    gpa.w += __shfl_xor(gpa.w, m);
    gpb.x += __shfl_xor(gpb.x, m);
    gpb.y += __shfl_xor(gpb.y, m);
    gpb.z += __shfl_xor(gpb.z, m);
    gpb.w += __shfl_xor(gpb.w, m);
  }
  __syncthreads();  // Ssh reads done; reuse as scratch
  float* gs = Ssh;  // [4 waves][128]
  int w = tid >> 6;
  if ((tid & 63) < 16) {
    ((float4*)gs)[w * 32 + jg] = gpa;
    ((float4*)gs)[w * 32 + 16 + jg] = gpb;
  }
  __syncthreads();
  if (tid < HD) {
    float s = gs[tid] + gs[128 + tid] + gs[256 + tid] + gs[384 + tid];
    atomicAdd(&gsum[tid], s);
  }
}

__global__ void k_final(const float* __restrict__ gsum, const float* __restrict__ Wd,
                        const float* __restrict__ bd, float* __restrict__ out) {
  int o = threadIdx.x;
  if (o < 32) {
    float acc = bd[o];
    const float invN = 1.f / (float)N_NODES;
    for (int d = 0; d < HD; ++d) acc = fmaf(gsum[d] * invN, Wd[d * 32 + o], acc);
    out[o] = acc;
  }
}

extern "C" void kernel_launch(void* const* d_in, const int* in_sizes, int n_in,
                              void* d_out, int out_size, void* d_ws, size_t ws_size,
                              hipStream_t stream) {
  (void)in_sizes; (void)n_in; (void)out_size; (void)ws_size;
  const float* x    = (const float*)d_in[0];
  const int* esrc   = (const int*)d_in[1];
  const int* edst   = (const int*)d_in[2];
  const float* Wp   = (const float*)d_in[3];
  const float* bp   = (const float*)d_in[4];
  const float* Wm   = (const float*)d_in[5];
  const float* bm   = (const float*)d_in[6];
  const float* Wu   = (const float*)d_in[7];
  const float* bu   = (const float*)d_in[8];
  const float* gam  = (const float*)d_in[9];
  const float* bet  = (const float*)d_in[10];
  const float* Wd   = (const float*)d_in[11];
  const float* bd   = (const float*)d_in[12];
  float* out = (float*)d_out;

  char* ws = (char*)d_ws;
  size_t off = 0;
  float* h0     = (float*)(ws + off); off += (size_t)N_NODES * HD * 4;
  float* a      = (float*)(ws + off); off += (size_t)N_NODES * HD * 4;
  float* b      = (float*)(ws + off); off += (size_t)N_NODES * HD * 4;
  float* pooled = (float*)(ws + off); off += (size_t)N_NODES * HD * 4;
  int* es       = (int*)(ws + off);   off += (size_t)N_EDGES * 4;
  int* deg      = (int*)(ws + off);   off += (size_t)N_NODES * 4;   // zeroed
  float* gsum   = (float*)(ws + off); off += 128 * 4;               // zeroed (adjacent)
  int* row_start= (int*)(ws + off);   off += (size_t)(N_NODES + 1) * 4;
  int* cursor   = (int*)(ws + off);   off += (size_t)N_NODES * 4;
  int* bsum     = (int*)(ws + off);   off += (size_t)NSCB * 4;
  int* boff     = (int*)(ws + off);   off += (size_t)NSCB * 4;

  hipMemsetAsync(deg, 0, (size_t)(N_NODES + 128) * 4, stream);
  k_proj<<<(N_NODES + TILE_N - 1) / TILE_N, 256, 0, stream>>>(x, Wp, bp, Wm, bm, h0, a, b);
  k_hist<<<(N_EDGES + 255) / 256, 256, 0, stream>>>(edst, deg);
  k_scan1<<<NSCB, 256, 0, stream>>>(deg, bsum);
  k_scan2<<<1, 256, 0, stream>>>(bsum, boff, row_start);
  k_scan3<<<NSCB, 256, 0, stream>>>(deg, boff, row_start, cursor);
  k_scatter<<<(N_EDGES + 255) / 256, 256, 0, stream>>>(esrc, edst, cursor, es);
  k_agg<<<(N_NODES + 3) / 4, 256, 0, stream>>>(a, b, es, row_start, pooled);
  k_upd<<<(N_NODES + TILE_N - 1) / TILE_N, 256, 0, stream>>>(h0, pooled, Wu, bu, gam, bet, gsum);
  k_final<<<1, 64, 0, stream>>>(gsum, Wd, bd, out);
}

// Round 6
// 255.558 us; speedup vs baseline: 3.1885x; 1.3496x over previous
//
#include <hip/hip_runtime.h>

#define N_NODES 50000
#define N_EDGES 640000
#define HD 128
#define TILE_N 128
#define NSCB 196  // ceil(50000/256)

typedef short bf16x8 __attribute__((ext_vector_type(8)));      // 8 bf16 = 4 VGPR (guide §3)
typedef float f32x4 __attribute__((ext_vector_type(4)));
typedef unsigned short u16x8 __attribute__((ext_vector_type(8)));
typedef unsigned short u16x4 __attribute__((ext_vector_type(4)));

__device__ __forceinline__ unsigned short f2bf(float f) {  // RNE f32 -> bf16
  unsigned u = __float_as_uint(f);
  return (unsigned short)((u + 0x7fffu + ((u >> 16) & 1u)) >> 16);
}
__device__ __forceinline__ float bf2f(unsigned short h) {
  return __uint_as_float(((unsigned)h) << 16);
}
// byte offset of logical (row, 16B-unit u) in a [128 rows][128 bf16] LDS tile.
// XOR swizzle spreads same-u column reads across 8 bank-quads (2-way = free).
// SINGLE source of truth: used by every stage/scatter/read/copy (rule #21).
__device__ __forceinline__ int swzb(int row, int u) {
  return row * 256 + ((u ^ (row & 7)) << 4);
}

// ---- MFMA building blocks: 4 waves, wave tile 64x64, 16x16x32 bf16 ----
__device__ __forceinline__ void load_A(const char* Ash, int lane, int wr, bf16x8 A[4][4]) {
  const int l15 = lane & 15, l4 = lane >> 4;
#pragma unroll
  for (int rt = 0; rt < 4; ++rt)
#pragma unroll
    for (int kk = 0; kk < 4; ++kk)
      A[rt][kk] = *(const bf16x8*)(Ash + swzb(wr * 64 + rt * 16 + l15, kk * 4 + l4));
}

__device__ __forceinline__ void mfma_AB(const bf16x8 A[4][4], const char* Bsh,
                                        int lane, int wc, f32x4 acc[4][4]) {
  const int l15 = lane & 15, l4 = lane >> 4;
#pragma unroll
  for (int ct = 0; ct < 4; ++ct) {
    bf16x8 B[4];
#pragma unroll
    for (int kk = 0; kk < 4; ++kk)
      B[kk] = *(const bf16x8*)(Bsh + swzb(wc * 64 + ct * 16 + l15, kk * 4 + l4));
#pragma unroll
    for (int rt = 0; rt < 4; ++rt)
#pragma unroll
      for (int kk = 0; kk < 4; ++kk)
        acc[rt][ct] =
            __builtin_amdgcn_mfma_f32_16x16x32_bf16(A[rt][kk], B[kk], acc[rt][ct], 0, 0, 0);
  }
}

// C/D layout (m89-verified): col=lane&15 (+16ct+64wc), row=(lane>>4)*4+e (+16rt+64wr).
__device__ __forceinline__ void scatter_acc(char* Tsh, int lane, int wr, int wc,
                                            const f32x4 acc[4][4]) {
  const int l15 = lane & 15, l4 = lane >> 4;
#pragma unroll
  for (int rt = 0; rt < 4; ++rt)
#pragma unroll
    for (int ct = 0; ct < 4; ++ct) {
      int c = wc * 64 + ct * 16 + l15;
#pragma unroll
      for (int e = 0; e < 4; ++e) {
        int r = wr * 64 + rt * 16 + l4 * 4 + e;
        *(unsigned short*)(Tsh + swzb(r, c >> 3) + (c & 7) * 2) = f2bf(acc[rt][ct][e]);
      }
    }
}

__device__ __forceinline__ void copy_out(const char* Tsh, unsigned short* __restrict__ g,
                                         int bnode0, int tid) {
#pragma unroll
  for (int c = 0; c < 8; ++c) {
    int ul = c * 256 + tid;
    int row = ul >> 4, u = ul & 15;
    if (bnode0 + row < N_NODES)
      *(u16x8*)(g + (size_t)(bnode0 + row) * HD + u * 8) = *(const u16x8*)(Tsh + swzb(row, u));
  }
}

// bf16 global [rows][128] -> swizzled LDS tile
__device__ __forceinline__ void stage_bf(const unsigned short* __restrict__ src, char* Tsh,
                                         int bnode0, int tid, bool guard) {
#pragma unroll
  for (int c = 0; c < 8; ++c) {
    int ul = c * 256 + tid;
    int row = ul >> 4, u = ul & 15;
    u16x8 v = {0, 0, 0, 0, 0, 0, 0, 0};
    if (!guard || (bnode0 + row < N_NODES))
      v = *(const u16x8*)(src + (size_t)(bnode0 + row) * HD + u * 8);
    *(u16x8*)(Tsh + swzb(row, u)) = v;
  }
}

// f32 global [rows][128] -> bf16 swizzled LDS tile
__device__ __forceinline__ void stage_xf(const float* __restrict__ src, char* Tsh,
                                         int bnode0, int tid) {
#pragma unroll
  for (int c = 0; c < 16; ++c) {
    int f4 = c * 256 + tid;
    int row = f4 >> 5, c4 = f4 & 31;
    float4 v = make_float4(0.f, 0.f, 0.f, 0.f);
    if (bnode0 + row < N_NODES) v = ((const float4*)src)[(size_t)(bnode0 + row) * 32 + c4];
    u16x4 p;
    p[0] = f2bf(v.x); p[1] = f2bf(v.y); p[2] = f2bf(v.z); p[3] = f2bf(v.w);
    *(u16x4*)(Tsh + swzb(row, c4 >> 1) + (c4 & 1) * 8) = p;
  }
}

// ---- one-shot: W^T bf16 slices: [WpT, WmaT, WmbT, Wu0T, Wu1T] each [128 n][128 k] ----
__global__ __launch_bounds__(128) void k_prew(const float* __restrict__ Wp,
                                              const float* __restrict__ Wm,
                                              const float* __restrict__ Wu,
                                              unsigned short* __restrict__ WT) {
  const int s = blockIdx.x;
  const float* src = (s == 0) ? Wp : (s == 1) ? Wm : (s == 2) ? (Wm + HD * HD)
                     : (s == 3) ? Wu : (Wu + HD * HD);
  const int n = threadIdx.x;
  unsigned short* dst = WT + (size_t)s * HD * HD + (size_t)n * HD;
  for (int kc = 0; kc < HD; kc += 8) {
    u16x8 p;
#pragma unroll
    for (int j = 0; j < 8; ++j) p[j] = f2bf(src[(size_t)(kc + j) * HD + n]);
    *(u16x8*)(dst + kc) = p;
  }
}

// h0 = x@Wp+bp ; a = h0@Wm[:H] ; b = h0@Wm[H:]+bm   (all bf16 out)
__global__ __launch_bounds__(256, 2) void k_proj(
    const float* __restrict__ x, const unsigned short* __restrict__ WT,
    const float* __restrict__ bp, const float* __restrict__ bm,
    unsigned short* __restrict__ h0, unsigned short* __restrict__ a,
    unsigned short* __restrict__ b) {
  __shared__ char Ssh[32768];
  __shared__ char Wsh[32768];
  const int tid = threadIdx.x, lane = tid & 63, wid = tid >> 6;
  const int wr = wid >> 1, wc = wid & 1, l15 = lane & 15;
  const int bnode0 = blockIdx.x * TILE_N;

  stage_xf(x, Ssh, bnode0, tid);
  stage_bf(WT, Wsh, 0, tid, false);  // WpT
  __syncthreads();

  bf16x8 A[4][4];
  f32x4 acc[4][4];
  load_A(Ssh, lane, wr, A);
#pragma unroll
  for (int ct = 0; ct < 4; ++ct) {
    float bv = bp[wc * 64 + ct * 16 + l15];
    f32x4 sv = {bv, bv, bv, bv};
#pragma unroll
    for (int rt = 0; rt < 4; ++rt) acc[rt][ct] = sv;
  }
  mfma_AB(A, Wsh, lane, wc, acc);          // h0
  __syncthreads();                          // x reads done
  scatter_acc(Ssh, lane, wr, wc, acc);      // h0 -> Ssh
  stage_bf(WT + 1 * HD * HD, Wsh, 0, tid, false);  // WmaT
  __syncthreads();
  copy_out(Ssh, h0, bnode0, tid);
  load_A(Ssh, lane, wr, A);                 // h0 frags (kept for a AND b)
#pragma unroll
  for (int ct = 0; ct < 4; ++ct) {
    f32x4 z = {0.f, 0.f, 0.f, 0.f};
#pragma unroll
    for (int rt = 0; rt < 4; ++rt) acc[rt][ct] = z;
  }
  mfma_AB(A, Wsh, lane, wc, acc);          // a
  __syncthreads();                          // copy_out(h0)+load_A done everywhere
  scatter_acc(Ssh, lane, wr, wc, acc);      // a -> Ssh
  stage_bf(WT + 2 * HD * HD, Wsh, 0, tid, false);  // WmbT
  __syncthreads();
  copy_out(Ssh, a, bnode0, tid);
#pragma unroll
  for (int ct = 0; ct < 4; ++ct) {
    float bv = bm[wc * 64 + ct * 16 + l15];
    f32x4 sv = {bv, bv, bv, bv};
#pragma unroll
    for (int rt = 0; rt < 4; ++rt) acc[rt][ct] = sv;
  }
  mfma_AB(A, Wsh, lane, wc, acc);          // b (A regs reused)
  __syncthreads();                          // copy_out(a) done everywhere
  scatter_acc(Ssh, lane, wr, wc, acc);      // b -> Ssh
  __syncthreads();
  copy_out(Ssh, b, bnode0, tid);
}

__global__ void k_hist(const int* __restrict__ dst, int* __restrict__ deg) {
  int e = blockIdx.x * 256 + threadIdx.x;
  if (e < N_EDGES) atomicAdd(&deg[dst[e]], 1);
}

__global__ __launch_bounds__(256) void k_scan1(const int* __restrict__ deg,
                                               int* __restrict__ bsum) {
  __shared__ int sh[256];
  int i = blockIdx.x * 256 + threadIdx.x;
  sh[threadIdx.x] = (i < N_NODES) ? deg[i] : 0;
  __syncthreads();
  for (int off = 128; off > 0; off >>= 1) {
    if (threadIdx.x < off) sh[threadIdx.x] += sh[threadIdx.x + off];
    __syncthreads();
  }
  if (threadIdx.x == 0) bsum[blockIdx.x] = sh[0];
}

__global__ __launch_bounds__(256) void k_scan2(const int* __restrict__ bsum,
                                               int* __restrict__ boff,
                                               int* __restrict__ row_start) {
  __shared__ int sh[256];
  int t = threadIdx.x;
  int v = (t < NSCB) ? bsum[t] : 0;
  sh[t] = v;
  __syncthreads();
  for (int off = 1; off < 256; off <<= 1) {
    int add = (t >= off) ? sh[t - off] : 0;
    __syncthreads();
    sh[t] += add;
    __syncthreads();
  }
  if (t < NSCB) boff[t] = sh[t] - v;
  if (t == 255) row_start[N_NODES] = sh[255];
}

__global__ __launch_bounds__(256) void k_scan3(const int* __restrict__ deg,
                                               const int* __restrict__ boff,
                                               int* __restrict__ row_start,
                                               int* __restrict__ cursor) {
  __shared__ int sh[256];
  int t = threadIdx.x;
  int i = blockIdx.x * 256 + t;
  int v = (i < N_NODES) ? deg[i] : 0;
  sh[t] = v;
  __syncthreads();
  for (int off = 1; off < 256; off <<= 1) {
    int add = (t >= off) ? sh[t - off] : 0;
    __syncthreads();
    sh[t] += add;
    __syncthreads();
  }
  if (i < N_NODES) {
    int ex = boff[blockIdx.x] + sh[t] - v;
    row_start[i] = ex;
    cursor[i] = ex;
  }
}

__global__ void k_scatter(const int* __restrict__ src, const int* __restrict__ dst,
                          int* __restrict__ cursor, int* __restrict__ es) {
  int e = blockIdx.x * 256 + threadIdx.x;
  if (e < N_EDGES) {
    int d = dst[e];
    int pos = atomicAdd(&cursor[d], 1);
    es[pos] = src[e];
  }
}

// pooled[n] = mean over in-edges of relu(a[src] + b[n]); a,b,pooled bf16
__global__ __launch_bounds__(256) void k_agg(const unsigned short* __restrict__ a,
                                             const unsigned short* __restrict__ b,
                                             const int* __restrict__ es,
                                             const int* __restrict__ row_start,
                                             unsigned short* __restrict__ pooled) {
  const int node = blockIdx.x * 4 + (threadIdx.x >> 6);
  const int lane = threadIdx.x & 63;
  const int s = row_start[node];
  const int e = row_start[node + 1];
  const unsigned bu = ((const unsigned*)(b + (size_t)node * HD))[lane];
  const float bx = bf2f((unsigned short)(bu & 0xffffu));
  const float by = bf2f((unsigned short)(bu >> 16));
  float ax = 0.f, ay = 0.f;
  int i = s;
  for (; i + 4 <= e; i += 4) {
    int s0 = es[i], s1 = es[i + 1], s2 = es[i + 2], s3 = es[i + 3];
    unsigned a0 = ((const unsigned*)(a + (size_t)s0 * HD))[lane];
    unsigned a1 = ((const unsigned*)(a + (size_t)s1 * HD))[lane];
    unsigned a2 = ((const unsigned*)(a + (size_t)s2 * HD))[lane];
    unsigned a3 = ((const unsigned*)(a + (size_t)s3 * HD))[lane];
    ax += fmaxf(bf2f((unsigned short)(a0 & 0xffffu)) + bx, 0.f);
    ay += fmaxf(bf2f((unsigned short)(a0 >> 16)) + by, 0.f);
    ax += fmaxf(bf2f((unsigned short)(a1 & 0xffffu)) + bx, 0.f);
    ay += fmaxf(bf2f((unsigned short)(a1 >> 16)) + by, 0.f);
    ax += fmaxf(bf2f((unsigned short)(a2 & 0xffffu)) + bx, 0.f);
    ay += fmaxf(bf2f((unsigned short)(a2 >> 16)) + by, 0.f);
    ax += fmaxf(bf2f((unsigned short)(a3 & 0xffffu)) + bx, 0.f);
    ay += fmaxf(bf2f((unsigned short)(a3 >> 16)) + by, 0.f);
  }
  for (; i < e; ++i) {
    unsigned a0 = ((const unsigned*)(a + (size_t)es[i] * HD))[lane];
    ax += fmaxf(bf2f((unsigned short)(a0 & 0xffffu)) + bx, 0.f);
    ay += fmaxf(bf2f((unsigned short)(a0 >> 16)) + by, 0.f);
  }
  const float inv = 1.f / fmaxf((float)(e - s), 1.f);
  unsigned o = (unsigned)f2bf(ax * inv) | ((unsigned)f2bf(ay * inv) << 16);
  ((unsigned*)(pooled + (size_t)node * HD))[lane] = o;
}

// upd = h0@Wu0 + pooled@Wu1 + bu ; hn = relu(h0+upd) ; LN ; graph-sum atomics
__global__ __launch_bounds__(256, 2) void k_upd(
    const unsigned short* __restrict__ h0, const unsigned short* __restrict__ pooled,
    const unsigned short* __restrict__ WT, const float* __restrict__ bu,
    const float* __restrict__ gamma, const float* __restrict__ beta,
    float* __restrict__ gsum) {
  __shared__ char Ssh[32768];
  __shared__ char Wsh[32768];
  const int tid = threadIdx.x, lane = tid & 63, wid = tid >> 6;
  const int wr = wid >> 1, wc = wid & 1, l15 = lane & 15, l4 = lane >> 4;
  const int bnode0 = blockIdx.x * TILE_N;

  stage_bf(pooled, Ssh, bnode0, tid, true);
  stage_bf(WT + 4 * HD * HD, Wsh, 0, tid, false);  // Wu1T
  __syncthreads();

  bf16x8 A[4][4];
  f32x4 acc[4][4];
  load_A(Ssh, lane, wr, A);
#pragma unroll
  for (int ct = 0; ct < 4; ++ct) {
    float bv = bu[wc * 64 + ct * 16 + l15];
    f32x4 sv = {bv, bv, bv, bv};
#pragma unroll
    for (int rt = 0; rt < 4; ++rt) acc[rt][ct] = sv;
  }
  mfma_AB(A, Wsh, lane, wc, acc);  // pooled@Wu1 + bu
  __syncthreads();
  stage_bf(h0, Ssh, bnode0, tid, true);
  stage_bf(WT + 3 * HD * HD, Wsh, 0, tid, false);  // Wu0T
  __syncthreads();
  load_A(Ssh, lane, wr, A);
  mfma_AB(A, Wsh, lane, wc, acc);  // += h0@Wu0
  __syncthreads();                 // Wsh free for partials

  // hn = relu(h0 + upd) in place; per-row sums (over this wave's 64-col half)
  float rsum[4][4], rsq[4][4];
#pragma unroll
  for (int rt = 0; rt < 4; ++rt)
#pragma unroll
    for (int e = 0; e < 4; ++e) {
      int r = wr * 64 + rt * 16 + l4 * 4 + e;
      float srow = 0.f, qrow = 0.f;
#pragma unroll
      for (int ct = 0; ct < 4; ++ct) {
        int c = wc * 64 + ct * 16 + l15;
        float hv = bf2f(*(const unsigned short*)(Ssh + swzb(r, c >> 3) + (c & 7) * 2));
        float v = fmaxf(hv + acc[rt][ct][e], 0.f);
        acc[rt][ct][e] = v;
        srow += v;
        qrow += v * v;
      }
#pragma unroll
      for (int m = 1; m < 16; m <<= 1) {
        srow += __shfl_xor(srow, m);
        qrow += __shfl_xor(qrow, m);
      }
      rsum[rt][e] = srow;
      rsq[rt][e] = qrow;
    }
  float* pS = (float*)Wsh;          // [128][2]
  float* pQ = (float*)(Wsh + 1024);
  if (l15 == 0) {
#pragma unroll
    for (int rt = 0; rt < 4; ++rt)
#pragma unroll
      for (int e = 0; e < 4; ++e) {
        int r = wr * 64 + rt * 16 + l4 * 4 + e;
        pS[r * 2 + wc] = rsum[rt][e];
        pQ[r * 2 + wc] = rsq[rt][e];
      }
  }
  __syncthreads();

  float g4[4], b4[4];
#pragma unroll
  for (int ct = 0; ct < 4; ++ct) {
    int c = wc * 64 + ct * 16 + l15;
    g4[ct] = gamma[c];
    b4[ct] = beta[c];
  }
  float gp[4] = {0.f, 0.f, 0.f, 0.f};
#pragma unroll
  for (int rt = 0; rt < 4; ++rt)
#pragma unroll
    for (int e = 0; e < 4; ++e) {
      int r = wr * 64 + rt * 16 + l4 * 4 + e;
      float s = pS[r * 2] + pS[r * 2 + 1];
      float q = pQ[r * 2] + pQ[r * 2 + 1];
      float mu = s * (1.f / 128.f);
      float var = q * (1.f / 128.f) - mu * mu;
      float rs = rsqrtf(var + 1e-6f);
      bool valid = (bnode0 + r) < N_NODES;
#pragma unroll
      for (int ct = 0; ct < 4; ++ct) {
        float v = (acc[rt][ct][e] - mu) * rs * g4[ct] + b4[ct];
        if (valid) gp[ct] += v;
      }
    }
#pragma unroll
  for (int ct = 0; ct < 4; ++ct) {
    gp[ct] += __shfl_xor(gp[ct], 16);
    gp[ct] += __shfl_xor(gp[ct], 32);
  }
  if (lane < 16) {
#pragma unroll
    for (int ct = 0; ct < 4; ++ct) atomicAdd(&gsum[wc * 64 + ct * 16 + lane], gp[ct]);
  }
}

__global__ void k_final(const float* __restrict__ gsum, const float* __restrict__ Wd,
                        const float* __restrict__ bd, float* __restrict__ out) {
  int o = threadIdx.x;
  if (o < 32) {
    float acc = bd[o];
    const float invN = 1.f / (float)N_NODES;
    for (int d = 0; d < HD; ++d) acc = fmaf(gsum[d] * invN, Wd[d * 32 + o], acc);
    out[o] = acc;
  }
}

extern "C" void kernel_launch(void* const* d_in, const int* in_sizes, int n_in,
                              void* d_out, int out_size, void* d_ws, size_t ws_size,
                              hipStream_t stream) {
  (void)in_sizes; (void)n_in; (void)out_size; (void)ws_size;
  const float* x    = (const float*)d_in[0];
  const int* esrc   = (const int*)d_in[1];
  const int* edst   = (const int*)d_in[2];
  const float* Wp   = (const float*)d_in[3];
  const float* bp   = (const float*)d_in[4];
  const float* Wm   = (const float*)d_in[5];
  const float* bm   = (const float*)d_in[6];
  const float* Wu   = (const float*)d_in[7];
  const float* bu   = (const float*)d_in[8];
  const float* gam  = (const float*)d_in[9];
  const float* bet  = (const float*)d_in[10];
  const float* Wd   = (const float*)d_in[11];
  const float* bd   = (const float*)d_in[12];
  float* out = (float*)d_out;

  char* ws = (char*)d_ws;
  size_t off = 0;
  unsigned short* WT     = (unsigned short*)(ws + off); off += 5 * (size_t)HD * HD * 2;  // 160KB
  unsigned short* h0     = (unsigned short*)(ws + off); off += (size_t)N_NODES * HD * 2;
  unsigned short* a      = (unsigned short*)(ws + off); off += (size_t)N_NODES * HD * 2;
  unsigned short* b      = (unsigned short*)(ws + off); off += (size_t)N_NODES * HD * 2;
  unsigned short* pooled = (unsigned short*)(ws + off); off += (size_t)N_NODES * HD * 2;
  int* es        = (int*)(ws + off);   off += (size_t)N_EDGES * 4;
  int* deg       = (int*)(ws + off);   off += (size_t)N_NODES * 4;  // zeroed
  float* gsum    = (float*)(ws + off); off += 128 * 4;              // zeroed (adjacent)
  int* row_start = (int*)(ws + off);   off += (size_t)(N_NODES + 1) * 4;
  int* cursor    = (int*)(ws + off);   off += (size_t)N_NODES * 4;
  int* bsum      = (int*)(ws + off);   off += (size_t)NSCB * 4;
  int* boff      = (int*)(ws + off);   off += (size_t)NSCB * 4;

  hipMemsetAsync(deg, 0, (size_t)(N_NODES + 128) * 4, stream);
  k_prew<<<5, 128, 0, stream>>>(Wp, Wm, Wu, WT);
  k_proj<<<(N_NODES + TILE_N - 1) / TILE_N, 256, 0, stream>>>(x, WT, bp, bm, h0, a, b);
  k_hist<<<(N_EDGES + 255) / 256, 256, 0, stream>>>(edst, deg);
  k_scan1<<<NSCB, 256, 0, stream>>>(deg, bsum);
  k_scan2<<<1, 256, 0, stream>>>(bsum, boff, row_start);
  k_scan3<<<NSCB, 256, 0, stream>>>(deg, boff, row_start, cursor);
  k_scatter<<<(N_EDGES + 255) / 256, 256, 0, stream>>>(esrc, edst, cursor, es);
  k_agg<<<N_NODES / 4, 256, 0, stream>>>(a, b, es, row_start, pooled);
  k_upd<<<(N_NODES + TILE_N - 1) / TILE_N, 256, 0, stream>>>(h0, pooled, WT, bu, gam, bet, gsum);
  k_final<<<1, 64, 0, stream>>>(gsum, Wd, bd, out);
}

// Round 7
// 222.318 us; speedup vs baseline: 3.6653x; 1.1495x over previous
//
#include <hip/hip_runtime.h>

#define N_NODES 50000
#define N_EDGES 640000
#define HD 128
#define TILE_N 128
#define NSCB 196  // ceil(50000/256)

typedef short bf16x8 __attribute__((ext_vector_type(8)));      // 8 bf16 = 4 VGPR (guide §3)
typedef float f32x4 __attribute__((ext_vector_type(4)));
typedef unsigned short u16x8 __attribute__((ext_vector_type(8)));
typedef unsigned short u16x4 __attribute__((ext_vector_type(4)));

__device__ __forceinline__ unsigned short f2bf(float f) {  // RNE f32 -> bf16
  unsigned u = __float_as_uint(f);
  return (unsigned short)((u + 0x7fffu + ((u >> 16) & 1u)) >> 16);
}
__device__ __forceinline__ float bf2f(unsigned short h) {
  return __uint_as_float(((unsigned)h) << 16);
}
// byte offset of logical (row, 16B-unit u) in a [128 rows][128 bf16] LDS tile.
// XOR swizzle spreads same-u column reads across 8 bank-quads (2-way = free).
// SINGLE source of truth: used by every stage/scatter/read/copy (rule #21).
__device__ __forceinline__ int swzb(int row, int u) {
  return row * 256 + ((u ^ (row & 7)) << 4);
}

// ---- MFMA building blocks: 4 waves, wave tile 64x64, 16x16x32 bf16 ----
__device__ __forceinline__ void load_A(const char* Ash, int lane, int wr, bf16x8 A[4][4]) {
  const int l15 = lane & 15, l4 = lane >> 4;
#pragma unroll
  for (int rt = 0; rt < 4; ++rt)
#pragma unroll
    for (int kk = 0; kk < 4; ++kk)
      A[rt][kk] = *(const bf16x8*)(Ash + swzb(wr * 64 + rt * 16 + l15, kk * 4 + l4));
}

__device__ __forceinline__ void mfma_AB(const bf16x8 A[4][4], const char* Bsh,
                                        int lane, int wc, f32x4 acc[4][4]) {
  const int l15 = lane & 15, l4 = lane >> 4;
#pragma unroll
  for (int ct = 0; ct < 4; ++ct) {
    bf16x8 B[4];
#pragma unroll
    for (int kk = 0; kk < 4; ++kk)
      B[kk] = *(const bf16x8*)(Bsh + swzb(wc * 64 + ct * 16 + l15, kk * 4 + l4));
#pragma unroll
    for (int rt = 0; rt < 4; ++rt)
#pragma unroll
      for (int kk = 0; kk < 4; ++kk)
        acc[rt][ct] =
            __builtin_amdgcn_mfma_f32_16x16x32_bf16(A[rt][kk], B[kk], acc[rt][ct], 0, 0, 0);
  }
}

// C/D layout (m89-verified): col=lane&15 (+16ct+64wc), row=(lane>>4)*4+e (+16rt+64wr).
__device__ __forceinline__ void scatter_acc(char* Tsh, int lane, int wr, int wc,
                                            const f32x4 acc[4][4]) {
  const int l15 = lane & 15, l4 = lane >> 4;
#pragma unroll
  for (int rt = 0; rt < 4; ++rt)
#pragma unroll
    for (int ct = 0; ct < 4; ++ct) {
      int c = wc * 64 + ct * 16 + l15;
#pragma unroll
      for (int e = 0; e < 4; ++e) {
        int r = wr * 64 + rt * 16 + l4 * 4 + e;
        *(unsigned short*)(Tsh + swzb(r, c >> 3) + (c & 7) * 2) = f2bf(acc[rt][ct][e]);
      }
    }
}

__device__ __forceinline__ void copy_out(const char* Tsh, unsigned short* __restrict__ g,
                                         int bnode0, int tid) {
#pragma unroll
  for (int c = 0; c < 8; ++c) {
    int ul = c * 256 + tid;
    int row = ul >> 4, u = ul & 15;
    if (bnode0 + row < N_NODES)
      *(u16x8*)(g + (size_t)(bnode0 + row) * HD + u * 8) = *(const u16x8*)(Tsh + swzb(row, u));
  }
}

// bf16 global [rows][128] -> swizzled LDS tile
__device__ __forceinline__ void stage_bf(const unsigned short* __restrict__ src, char* Tsh,
                                         int bnode0, int tid, bool guard) {
#pragma unroll
  for (int c = 0; c < 8; ++c) {
    int ul = c * 256 + tid;
    int row = ul >> 4, u = ul & 15;
    u16x8 v = {0, 0, 0, 0, 0, 0, 0, 0};
    if (!guard || (bnode0 + row < N_NODES))
      v = *(const u16x8*)(src + (size_t)(bnode0 + row) * HD + u * 8);
    *(u16x8*)(Tsh + swzb(row, u)) = v;
  }
}

// f32 global [rows][128] -> bf16 swizzled LDS tile
__device__ __forceinline__ void stage_xf(const float* __restrict__ src, char* Tsh,
                                         int bnode0, int tid) {
#pragma unroll
  for (int c = 0; c < 16; ++c) {
    int f4 = c * 256 + tid;
    int row = f4 >> 5, c4 = f4 & 31;
    float4 v = make_float4(0.f, 0.f, 0.f, 0.f);
    if (bnode0 + row < N_NODES) v = ((const float4*)src)[(size_t)(bnode0 + row) * 32 + c4];
    u16x4 p;
    p[0] = f2bf(v.x); p[1] = f2bf(v.y); p[2] = f2bf(v.z); p[3] = f2bf(v.w);
    *(u16x4*)(Tsh + swzb(row, c4 >> 1) + (c4 & 1) * 8) = p;
  }
}

// ---- one-shot: W^T bf16 slices: [WpT, WmaT, WmbT, Wu0T, Wu1T] each [128 n][128 k] ----
__global__ __launch_bounds__(128) void k_prew(const float* __restrict__ Wp,
                                              const float* __restrict__ Wm,
                                              const float* __restrict__ Wu,
                                              unsigned short* __restrict__ WT) {
  const int s = blockIdx.x;
  const float* src = (s == 0) ? Wp : (s == 1) ? Wm : (s == 2) ? (Wm + HD * HD)
                     : (s == 3) ? Wu : (Wu + HD * HD);
  const int n = threadIdx.x;
  unsigned short* dst = WT + (size_t)s * HD * HD + (size_t)n * HD;
  for (int kc = 0; kc < HD; kc += 8) {
    u16x8 p;
#pragma unroll
    for (int j = 0; j < 8; ++j) p[j] = f2bf(src[(size_t)(kc + j) * HD + n]);
    *(u16x8*)(dst + kc) = p;
  }
}

// h0 = x@Wp+bp ; a = h0@Wm[:H] ; b = h0@Wm[H:]+bm   (all bf16 out)
__global__ __launch_bounds__(256, 2) void k_proj(
    const float* __restrict__ x, const unsigned short* __restrict__ WT,
    const float* __restrict__ bp, const float* __restrict__ bm,
    unsigned short* __restrict__ h0, unsigned short* __restrict__ a,
    unsigned short* __restrict__ b) {
  __shared__ char Ssh[32768];
  __shared__ char Wsh[32768];
  const int tid = threadIdx.x, lane = tid & 63, wid = tid >> 6;
  const int wr = wid >> 1, wc = wid & 1, l15 = lane & 15;
  const int bnode0 = blockIdx.x * TILE_N;

  stage_xf(x, Ssh, bnode0, tid);
  stage_bf(WT, Wsh, 0, tid, false);  // WpT
  __syncthreads();

  bf16x8 A[4][4];
  f32x4 acc[4][4];
  load_A(Ssh, lane, wr, A);
#pragma unroll
  for (int ct = 0; ct < 4; ++ct) {
    float bv = bp[wc * 64 + ct * 16 + l15];
    f32x4 sv = {bv, bv, bv, bv};
#pragma unroll
    for (int rt = 0; rt < 4; ++rt) acc[rt][ct] = sv;
  }
  mfma_AB(A, Wsh, lane, wc, acc);          // h0
  __syncthreads();                          // x reads done
  scatter_acc(Ssh, lane, wr, wc, acc);      // h0 -> Ssh
  stage_bf(WT + 1 * HD * HD, Wsh, 0, tid, false);  // WmaT
  __syncthreads();
  copy_out(Ssh, h0, bnode0, tid);
  load_A(Ssh, lane, wr, A);                 // h0 frags (kept for a AND b)
#pragma unroll
  for (int ct = 0; ct < 4; ++ct) {
    f32x4 z = {0.f, 0.f, 0.f, 0.f};
#pragma unroll
    for (int rt = 0; rt < 4; ++rt) acc[rt][ct] = z;
  }
  mfma_AB(A, Wsh, lane, wc, acc);          // a
  __syncthreads();                          // copy_out(h0)+load_A done everywhere
  scatter_acc(Ssh, lane, wr, wc, acc);      // a -> Ssh
  stage_bf(WT + 2 * HD * HD, Wsh, 0, tid, false);  // WmbT
  __syncthreads();
  copy_out(Ssh, a, bnode0, tid);
#pragma unroll
  for (int ct = 0; ct < 4; ++ct) {
    float bv = bm[wc * 64 + ct * 16 + l15];
    f32x4 sv = {bv, bv, bv, bv};
#pragma unroll
    for (int rt = 0; rt < 4; ++rt) acc[rt][ct] = sv;
  }
  mfma_AB(A, Wsh, lane, wc, acc);          // b (A regs reused)
  __syncthreads();                          // copy_out(a) done everywhere
  scatter_acc(Ssh, lane, wr, wc, acc);      // b -> Ssh
  __syncthreads();
  copy_out(Ssh, b, bnode0, tid);
}

// pos_e[e] = slot of edge e within its destination's segment (single atomic pass)
__global__ void k_hist(const int* __restrict__ dst, int* __restrict__ deg,
                       int* __restrict__ pos_e) {
  int e = blockIdx.x * 256 + threadIdx.x;
  if (e < N_EDGES) pos_e[e] = atomicAdd(&deg[dst[e]], 1);
}

__global__ __launch_bounds__(256) void k_scan1(const int* __restrict__ deg,
                                               int* __restrict__ bsum) {
  __shared__ int sh[256];
  int i = blockIdx.x * 256 + threadIdx.x;
  sh[threadIdx.x] = (i < N_NODES) ? deg[i] : 0;
  __syncthreads();
  for (int off = 128; off > 0; off >>= 1) {
    if (threadIdx.x < off) sh[threadIdx.x] += sh[threadIdx.x + off];
    __syncthreads();
  }
  if (threadIdx.x == 0) bsum[blockIdx.x] = sh[0];
}

__global__ __launch_bounds__(256) void k_scan2(const int* __restrict__ bsum,
                                               int* __restrict__ boff,
                                               int* __restrict__ row_start) {
  __shared__ int sh[256];
  int t = threadIdx.x;
  int v = (t < NSCB) ? bsum[t] : 0;
  sh[t] = v;
  __syncthreads();
  for (int off = 1; off < 256; off <<= 1) {
    int add = (t >= off) ? sh[t - off] : 0;
    __syncthreads();
    sh[t] += add;
    __syncthreads();
  }
  if (t < NSCB) boff[t] = sh[t] - v;
  if (t == 255) row_start[N_NODES] = sh[255];
}

__global__ __launch_bounds__(256) void k_scan3(const int* __restrict__ deg,
                                               const int* __restrict__ boff,
                                               int* __restrict__ row_start) {
  __shared__ int sh[256];
  int t = threadIdx.x;
  int i = blockIdx.x * 256 + t;
  int v = (i < N_NODES) ? deg[i] : 0;
  sh[t] = v;
  __syncthreads();
  for (int off = 1; off < 256; off <<= 1) {
    int add = (t >= off) ? sh[t - off] : 0;
    __syncthreads();
    sh[t] += add;
    __syncthreads();
  }
  if (i < N_NODES) row_start[i] = boff[blockIdx.x] + sh[t] - v;
}

// atomic-free scatter: slot precomputed in k_hist
__global__ void k_scatter(const int* __restrict__ src, const int* __restrict__ dst,
                          const int* __restrict__ pos_e, const int* __restrict__ row_start,
                          int* __restrict__ es) {
  int e = blockIdx.x * 256 + threadIdx.x;
  if (e < N_EDGES) {
    int d = dst[e];
    es[row_start[d] + pos_e[e]] = src[e];
  }
}

// pooled[n] = mean over in-edges of relu(a[src] + b[n]); a,b,pooled bf16
__global__ __launch_bounds__(256) void k_agg(const unsigned short* __restrict__ a,
                                             const unsigned short* __restrict__ b,
                                             const int* __restrict__ es,
                                             const int* __restrict__ row_start,
                                             unsigned short* __restrict__ pooled) {
  const int node = blockIdx.x * 4 + (threadIdx.x >> 6);
  const int lane = threadIdx.x & 63;
  const int s = row_start[node];
  const int e = row_start[node + 1];
  const unsigned bu = ((const unsigned*)(b + (size_t)node * HD))[lane];
  const float bx = bf2f((unsigned short)(bu & 0xffffu));
  const float by = bf2f((unsigned short)(bu >> 16));
  float ax = 0.f, ay = 0.f;
  int i = s;
  for (; i + 8 <= e; i += 8) {
    unsigned av[8];
#pragma unroll
    for (int j = 0; j < 8; ++j)
      av[j] = ((const unsigned*)(a + (size_t)es[i + j] * HD))[lane];
#pragma unroll
    for (int j = 0; j < 8; ++j) {
      ax += fmaxf(bf2f((unsigned short)(av[j] & 0xffffu)) + bx, 0.f);
      ay += fmaxf(bf2f((unsigned short)(av[j] >> 16)) + by, 0.f);
    }
  }
  for (; i + 4 <= e; i += 4) {
    unsigned av[4];
#pragma unroll
    for (int j = 0; j < 4; ++j)
      av[j] = ((const unsigned*)(a + (size_t)es[i + j] * HD))[lane];
#pragma unroll
    for (int j = 0; j < 4; ++j) {
      ax += fmaxf(bf2f((unsigned short)(av[j] & 0xffffu)) + bx, 0.f);
      ay += fmaxf(bf2f((unsigned short)(av[j] >> 16)) + by, 0.f);
    }
  }
  for (; i < e; ++i) {
    unsigned a0 = ((const unsigned*)(a + (size_t)es[i] * HD))[lane];
    ax += fmaxf(bf2f((unsigned short)(a0 & 0xffffu)) + bx, 0.f);
    ay += fmaxf(bf2f((unsigned short)(a0 >> 16)) + by, 0.f);
  }
  const float inv = 1.f / fmaxf((float)(e - s), 1.f);
  unsigned o = (unsigned)f2bf(ax * inv) | ((unsigned)f2bf(ay * inv) << 16);
  ((unsigned*)(pooled + (size_t)node * HD))[lane] = o;
}

// upd = h0@Wu0 + pooled@Wu1 + bu ; hn = relu(h0+upd) ; LN ; graph-sum atomics
__global__ __launch_bounds__(256, 2) void k_upd(
    const unsigned short* __restrict__ h0, const unsigned short* __restrict__ pooled,
    const unsigned short* __restrict__ WT, const float* __restrict__ bu,
    const float* __restrict__ gamma, const float* __restrict__ beta,
    float* __restrict__ gsum) {
  __shared__ char Ssh[32768];
  __shared__ char Wsh[32768];
  const int tid = threadIdx.x, lane = tid & 63, wid = tid >> 6;
  const int wr = wid >> 1, wc = wid & 1, l15 = lane & 15, l4 = lane >> 4;
  const int bnode0 = blockIdx.x * TILE_N;

  stage_bf(pooled, Ssh, bnode0, tid, true);
  stage_bf(WT + 4 * HD * HD, Wsh, 0, tid, false);  // Wu1T
  __syncthreads();

  bf16x8 A[4][4];
  f32x4 acc[4][4];
  load_A(Ssh, lane, wr, A);
#pragma unroll
  for (int ct = 0; ct < 4; ++ct) {
    float bv = bu[wc * 64 + ct * 16 + l15];
    f32x4 sv = {bv, bv, bv, bv};
#pragma unroll
    for (int rt = 0; rt < 4; ++rt) acc[rt][ct] = sv;
  }
  mfma_AB(A, Wsh, lane, wc, acc);  // pooled@Wu1 + bu
  __syncthreads();
  stage_bf(h0, Ssh, bnode0, tid, true);
  stage_bf(WT + 3 * HD * HD, Wsh, 0, tid, false);  // Wu0T
  __syncthreads();
  load_A(Ssh, lane, wr, A);
  mfma_AB(A, Wsh, lane, wc, acc);  // += h0@Wu0
  __syncthreads();                 // Wsh free for partials

  // hn = relu(h0 + upd) in place; per-row sums (over this wave's 64-col half)
  float rsum[4][4], rsq[4][4];
#pragma unroll
  for (int rt = 0; rt < 4; ++rt)
#pragma unroll
    for (int e = 0; e < 4; ++e) {
      int r = wr * 64 + rt * 16 + l4 * 4 + e;
      float srow = 0.f, qrow = 0.f;
#pragma unroll
      for (int ct = 0; ct < 4; ++ct) {
        int c = wc * 64 + ct * 16 + l15;
        float hv = bf2f(*(const unsigned short*)(Ssh + swzb(r, c >> 3) + (c & 7) * 2));
        float v = fmaxf(hv + acc[rt][ct][e], 0.f);
        acc[rt][ct][e] = v;
        srow += v;
        qrow += v * v;
      }
#pragma unroll
      for (int m = 1; m < 16; m <<= 1) {
        srow += __shfl_xor(srow, m);
        qrow += __shfl_xor(qrow, m);
      }
      rsum[rt][e] = srow;
      rsq[rt][e] = qrow;
    }
  float* pS = (float*)Wsh;          // [128][2]
  float* pQ = (float*)(Wsh + 1024);
  if (l15 == 0) {
#pragma unroll
    for (int rt = 0; rt < 4; ++rt)
#pragma unroll
      for (int e = 0; e < 4; ++e) {
        int r = wr * 64 + rt * 16 + l4 * 4 + e;
        pS[r * 2 + wc] = rsum[rt][e];
        pQ[r * 2 + wc] = rsq[rt][e];
      }
  }
  __syncthreads();

  float g4[4], b4[4];
#pragma unroll
  for (int ct = 0; ct < 4; ++ct) {
    int c = wc * 64 + ct * 16 + l15;
    g4[ct] = gamma[c];
    b4[ct] = beta[c];
  }
  float gp[4] = {0.f, 0.f, 0.f, 0.f};
#pragma unroll
  for (int rt = 0; rt < 4; ++rt)
#pragma unroll
    for (int e = 0; e < 4; ++e) {
      int r = wr * 64 + rt * 16 + l4 * 4 + e;
      float s = pS[r * 2] + pS[r * 2 + 1];
      float q = pQ[r * 2] + pQ[r * 2 + 1];
      float mu = s * (1.f / 128.f);
      float var = q * (1.f / 128.f) - mu * mu;
      float rs = rsqrtf(var + 1e-6f);
      bool valid = (bnode0 + r) < N_NODES;
#pragma unroll
      for (int ct = 0; ct < 4; ++ct) {
        float v = (acc[rt][ct][e] - mu) * rs * g4[ct] + b4[ct];
        if (valid) gp[ct] += v;
      }
    }
#pragma unroll
  for (int ct = 0; ct < 4; ++ct) {
    gp[ct] += __shfl_xor(gp[ct], 16);
    gp[ct] += __shfl_xor(gp[ct], 32);
  }
  if (lane < 16) {
#pragma unroll
    for (int ct = 0; ct < 4; ++ct) atomicAdd(&gsum[wc * 64 + ct * 16 + lane], gp[ct]);
  }
}

__global__ void k_final(const float* __restrict__ gsum, const float* __restrict__ Wd,
                        const float* __restrict__ bd, float* __restrict__ out) {
  int o = threadIdx.x;
  if (o < 32) {
    float acc = bd[o];
    const float invN = 1.f / (float)N_NODES;
    for (int d = 0; d < HD; ++d) acc = fmaf(gsum[d] * invN, Wd[d * 32 + o], acc);
    out[o] = acc;
  }
}

extern "C" void kernel_launch(void* const* d_in, const int* in_sizes, int n_in,
                              void* d_out, int out_size, void* d_ws, size_t ws_size,
                              hipStream_t stream) {
  (void)in_sizes; (void)n_in; (void)out_size; (void)ws_size;
  const float* x    = (const float*)d_in[0];
  const int* esrc   = (const int*)d_in[1];
  const int* edst   = (const int*)d_in[2];
  const float* Wp   = (const float*)d_in[3];
  const float* bp   = (const float*)d_in[4];
  const float* Wm   = (const float*)d_in[5];
  const float* bm   = (const float*)d_in[6];
  const float* Wu   = (const float*)d_in[7];
  const float* bu   = (const float*)d_in[8];
  const float* gam  = (const float*)d_in[9];
  const float* bet  = (const float*)d_in[10];
  const float* Wd   = (const float*)d_in[11];
  const float* bd   = (const float*)d_in[12];
  float* out = (float*)d_out;

  char* ws = (char*)d_ws;
  size_t off = 0;
  unsigned short* WT     = (unsigned short*)(ws + off); off += 5 * (size_t)HD * HD * 2;  // 160KB
  unsigned short* h0     = (unsigned short*)(ws + off); off += (size_t)N_NODES * HD * 2;
  unsigned short* a      = (unsigned short*)(ws + off); off += (size_t)N_NODES * HD * 2;
  unsigned short* b      = (unsigned short*)(ws + off); off += (size_t)N_NODES * HD * 2;
  unsigned short* pooled = (unsigned short*)(ws + off); off += (size_t)N_NODES * HD * 2;
  int* es        = (int*)(ws + off);   off += (size_t)N_EDGES * 4;
  int* pos_e     = (int*)(ws + off);   off += (size_t)N_EDGES * 4;
  int* deg       = (int*)(ws + off);   off += (size_t)N_NODES * 4;  // zeroed
  float* gsum    = (float*)(ws + off); off += 128 * 4;              // zeroed (adjacent)
  int* row_start = (int*)(ws + off);   off += (size_t)(N_NODES + 1) * 4;
  int* bsum      = (int*)(ws + off);   off += (size_t)NSCB * 4;
  int* boff      = (int*)(ws + off);   off += (size_t)NSCB * 4;

  hipMemsetAsync(deg, 0, (size_t)(N_NODES + 128) * 4, stream);
  k_prew<<<5, 128, 0, stream>>>(Wp, Wm, Wu, WT);
  k_proj<<<(N_NODES + TILE_N - 1) / TILE_N, 256, 0, stream>>>(x, WT, bp, bm, h0, a, b);
  k_hist<<<(N_EDGES + 255) / 256, 256, 0, stream>>>(edst, deg, pos_e);
  k_scan1<<<NSCB, 256, 0, stream>>>(deg, bsum);
  k_scan2<<<1, 256, 0, stream>>>(bsum, boff, row_start);
  k_scan3<<<NSCB, 256, 0, stream>>>(deg, boff, row_start);
  k_scatter<<<(N_EDGES + 255) / 256, 256, 0, stream>>>(esrc, edst, pos_e, row_start, es);
  k_agg<<<N_NODES / 4, 256, 0, stream>>>(a, b, es, row_start, pooled);
  k_upd<<<(N_NODES + TILE_N - 1) / TILE_N, 256, 0, stream>>>(h0, pooled, WT, bu, gam, bet, gsum);
  k_final<<<1, 64, 0, stream>>>(gsum, Wd, bd, out);
}